// Round 1
// baseline (352.467 us; speedup 1.0000x reference)
//
#include <hip/hip_runtime.h>
#include <hip/hip_cooperative_groups.h>

namespace cg = cooperative_groups;

#define NC 320   // coalition size
#define DIM 512

// ===========================================================================
// fused_all: single cooperative dispatch, grid 656 x 256.
//   phase 1 (b==blockIdx): big1 body  — split-K q/k partials (b<640) + hpart
//            (b>=640). block 0 thread 0 also zeroes out[0] (replaces memset).
//   grid.sync()
//   phase 2 (b<320): reduce_qk body — q/k = sum of 8 partials + bias.
//   grid.sync()
//   phase 3 (b<520): scores_u body — split-K S partials (b<200) + u/uw
//            (b>=200, atomics into out).
//   grid.sync()
//   phase 4 (b<320): row_ops3 body — softmax shift + scans + contraction,
//            one atomicAdd(out) per row.
// All bodies are the verified R4 bodies, unchanged arithmetic order.
// LDS: 2*32*68*4 + (320+320+321+12)*4 = 21.3 KB -> >=7 blocks/CU by LDS.
// __launch_bounds__(256,3) -> >=3 waves/SIMD -> 3 blocks/CU co-resident,
// 3*256=768 >= 656, cooperative launch validates.
// ===========================================================================
__global__ __launch_bounds__(256, 3) void fused_all(
    const float* __restrict__ x,
    const float* __restrict__ Wq, const float* __restrict__ bq,
    const float* __restrict__ Wk, const float* __restrict__ bk,
    const float* __restrict__ Wv, const float* __restrict__ bv,
    const float* __restrict__ Wc, const float* __restrict__ bc,
    float* __restrict__ partQK,   // [16][NC][DIM]
    float* __restrict__ partS,    // [8][NC][NC]
    float* __restrict__ qbuf, float* __restrict__ kbuf,
    float* __restrict__ hpart,    // [16][DIM]
    float* __restrict__ u,        // [NC]
    float* __restrict__ out)
{
  cg::grid_group grid = cg::this_grid();

  const int b    = blockIdx.x;
  const int t    = threadIdx.x;
  const int lane = t & 63;
  const int wave = t >> 6;

  __shared__ __align__(16) float As[32][68];   // [kk][row]
  __shared__ __align__(16) float Bs[32][68];   // [kk][col]
  __shared__ float e[NC];
  __shared__ float Warr[NC];
  __shared__ float Csuf[NC + 1];
  __shared__ float wred[12];

  // ------------------------- phase 1: big1 body ---------------------------
  if (b == 0 && t == 0) out[0] = 0.f;          // replaces hipMemsetAsync

  if (b >= 640) {   // ---- hpart ----
    const int d0 = (b - 640) * 32;
    for (int ei = t; ei < DIM; ei += 256) {
      float s = 0.f;
      #pragma unroll
      for (int d = 0; d < 32; ++d)
        s = fmaf(Wv[(d0 + d) * DIM + ei], Wc[d0 + d], s);
      hpart[(b - 640) * DIM + ei] = s;
    }
  } else {          // ---- split-K gemm partials (verified) ----
    const int z   = b / 40;
    const int rem = b % 40;
    const int i0  = (rem / 8) * 64;
    const int c0  = (rem % 8) * 64;
    const float* __restrict__ W = (z & 8) ? Wk : Wq;
    const int kb = (z & 7) * 64;

    const int sr = t >> 2;            // staged row/col 0..63
    const int kc = (t & 3) << 3;      // staged k offset 0,8,16,24
    const int ty = t >> 4;            // 0..15 row quad
    const int tx = t & 15;            // 0..15 col quad

    float acc[4][4] = {};
    const float* xp = x + (i0 + sr) * DIM + kc;
    const float* wp = W + (c0 + sr) * DIM + kc;

    for (int k0 = kb; k0 < kb + 64; k0 += 32) {
      const float4 xa = *(const float4*)(xp + k0);
      const float4 xb = *(const float4*)(xp + k0 + 4);
      const float4 wa = *(const float4*)(wp + k0);
      const float4 wb = *(const float4*)(wp + k0 + 4);
      __syncthreads();
      As[kc+0][sr]=xa.x; As[kc+1][sr]=xa.y; As[kc+2][sr]=xa.z; As[kc+3][sr]=xa.w;
      As[kc+4][sr]=xb.x; As[kc+5][sr]=xb.y; As[kc+6][sr]=xb.z; As[kc+7][sr]=xb.w;
      Bs[kc+0][sr]=wa.x; Bs[kc+1][sr]=wa.y; Bs[kc+2][sr]=wa.z; Bs[kc+3][sr]=wa.w;
      Bs[kc+4][sr]=wb.x; Bs[kc+5][sr]=wb.y; Bs[kc+6][sr]=wb.z; Bs[kc+7][sr]=wb.w;
      __syncthreads();
      #pragma unroll
      for (int kk = 0; kk < 32; ++kk) {
        const float4 a4 = *(const float4*)&As[kk][ty * 4];
        const float4 b4 = *(const float4*)&Bs[kk][tx * 4];
        const float a[4] = {a4.x, a4.y, a4.z, a4.w};
        const float bb[4] = {b4.x, b4.y, b4.z, b4.w};
        #pragma unroll
        for (int i = 0; i < 4; ++i)
          #pragma unroll
          for (int j = 0; j < 4; ++j)
            acc[i][j] = fmaf(a[i], bb[j], acc[i][j]);
      }
    }
    float* outq = partQK + (size_t)z * NC * DIM;
    #pragma unroll
    for (int i = 0; i < 4; ++i) {
      float4 o = {acc[i][0], acc[i][1], acc[i][2], acc[i][3]};
      *(float4*)&outq[(i0 + ty*4 + i) * DIM + c0 + tx*4] = o;
    }
  }

  grid.sync();

  // ----------------------- phase 2: reduce_qk body ------------------------
  if (b < 320) {
    const int mat = b / 160;
    const int f   = (b % 160) * 256 + t;   // float4 index
    const int row = f >> 7;                // 128 float4 per row
    const int col = (f & 127) * 4;
    const float* bias = mat ? bk : bq;
    float4 s = *(const float4*)&bias[col];
    const size_t off = (size_t)row * DIM + col;
    #pragma unroll
    for (int sp = 0; sp < 8; ++sp) {
      const float4 p = *(const float4*)&partQK[(size_t)(mat*8+sp) * NC * DIM + off];
      s.x += p.x; s.y += p.y; s.z += p.z; s.w += p.w;
    }
    float* o = mat ? kbuf : qbuf;
    *(float4*)&o[off] = s;
  }

  grid.sync();

  // ----------------------- phase 3: scores_u body -------------------------
  if (b < 520) {
    if (b >= 200) {   // ---- u / uw ----
      const int r = b - 200;

      float cp = bv[t] * Wc[t] + bv[t + 256] * Wc[t + 256];
      float su = 0.f, sw = 0.f;
      for (int ei = t; ei < DIM; ei += 256) {
        float hs = 0.f;
        #pragma unroll
        for (int sp = 0; sp < 16; ++sp) hs += hpart[sp * DIM + ei];
        const float xv = x[r * DIM + ei];
        su = fmaf(xv, hs, su);
        sw = fmaf(xv, Wc[DIM + ei], sw);
      }
      #pragma unroll
      for (int off = 32; off; off >>= 1) {
        cp += __shfl_down(cp, off);
        su += __shfl_down(su, off);
        sw += __shfl_down(sw, off);
      }
      if (lane == 0) { wred[wave] = cp; wred[4 + wave] = su; wred[8 + wave] = sw; }
      __syncthreads();
      if (t == 0) {
        const float c  = wred[0] + wred[1] + wred[2] + wred[3];
        const float sU = wred[4] + wred[5] + wred[6] + wred[7];
        float sW = wred[8] + wred[9] + wred[10] + wred[11];
        u[r] = sU + c;
        if (r == 0) sW += (float)NC * bc[0];
        atomicAdd(out, sW);
      }
    } else {          // ---- scores partials (verified) ----
      const int z   = b / 25;
      const int rem = b % 25;
      const int i0  = (rem / 5) * 64;
      const int j0  = (rem % 5) * 64;
      const int kb  = z * 64;

      const int sr = t >> 2;
      const int kc = (t & 3) << 3;
      const int ty = t >> 4;
      const int tx = t & 15;

      float acc[4][4] = {};
      const float* qp = qbuf + (i0 + sr) * DIM + kc;
      const float* kp = kbuf + (j0 + sr) * DIM + kc;

      for (int k0 = kb; k0 < kb + 64; k0 += 32) {
        const float4 qa  = *(const float4*)(qp + k0);
        const float4 qb2 = *(const float4*)(qp + k0 + 4);
        const float4 ka  = *(const float4*)(kp + k0);
        const float4 kb4 = *(const float4*)(kp + k0 + 4);
        __syncthreads();
        As[kc+0][sr]=qa.x;  As[kc+1][sr]=qa.y;  As[kc+2][sr]=qa.z;  As[kc+3][sr]=qa.w;
        As[kc+4][sr]=qb2.x; As[kc+5][sr]=qb2.y; As[kc+6][sr]=qb2.z; As[kc+7][sr]=qb2.w;
        Bs[kc+0][sr]=ka.x;  Bs[kc+1][sr]=ka.y;  Bs[kc+2][sr]=ka.z;  Bs[kc+3][sr]=ka.w;
        Bs[kc+4][sr]=kb4.x; Bs[kc+5][sr]=kb4.y; Bs[kc+6][sr]=kb4.z; Bs[kc+7][sr]=kb4.w;
        __syncthreads();
        #pragma unroll
        for (int kk = 0; kk < 32; ++kk) {
          const float4 a4 = *(const float4*)&As[kk][ty * 4];
          const float4 b4 = *(const float4*)&Bs[kk][tx * 4];
          const float a[4] = {a4.x, a4.y, a4.z, a4.w};
          const float bb[4] = {b4.x, b4.y, b4.z, b4.w};
          #pragma unroll
          for (int i = 0; i < 4; ++i)
            #pragma unroll
            for (int j = 0; j < 4; ++j)
              acc[i][j] = fmaf(a[i], bb[j], acc[i][j]);
        }
      }
      float* outs = partS + (size_t)z * NC * NC;
      #pragma unroll
      for (int i = 0; i < 4; ++i) {
        float4 o = {acc[i][0], acc[i][1], acc[i][2], acc[i][3]};
        *(float4*)&outs[(i0 + ty*4 + i) * NC + j0 + tx*4] = o;
      }
    }
  }

  grid.sync();

  // ----------------------- phase 4: row_ops3 body -------------------------
  if (b < 320) {
    const int i = b;

    const float scale = 0.044194173824159216f;  // 1/sqrt(512)
    for (int kk = t; kk < NC; kk += 256) {
      float s = 0.f;
      #pragma unroll
      for (int sp = 0; sp < 8; ++sp)
        s += partS[(size_t)sp * NC * NC + i * NC + kk];
      e[kk] = s * scale;
    }
    __syncthreads();

    float m = -1e30f;
    for (int kk = t; kk < NC; kk += 256) m = fmaxf(m, e[kk]);
    #pragma unroll
    for (int off = 32; off; off >>= 1) m = fmaxf(m, __shfl_down(m, off));
    if (lane == 0) wred[wave] = m;
    __syncthreads();
    m = fmaxf(fmaxf(wred[0], wred[1]), fmaxf(wred[2], wred[3]));

    for (int kk = t; kk < NC; kk += 256) e[kk] = __expf(e[kk] - m);
    __syncthreads();

    if (wave == 0) {
      float carry = 0.f;
      #pragma unroll
      for (int c = 0; c < 5; ++c) {
        const int idx = c * 64 + lane;
        float val = e[idx];
        #pragma unroll
        for (int off = 1; off < 64; off <<= 1) {
          const float nv = __shfl_up(val, off);
          if (lane >= off) val += nv;
        }
        const float incl = val + carry;       // prefix sum S[idx+1]
        const int j = idx + 1;
        if (j < NC) Warr[j] = (j > i) ? 1.f / ((float)j * incl) : 0.f;
        carry += __shfl(val, 63);
      }
      if (lane == 0) Warr[0] = 0.f;

      carry = 0.f;
      #pragma unroll
      for (int c = 4; c >= 0; --c) {
        const int idx = c * 64 + lane;
        float val = Warr[idx];
        #pragma unroll
        for (int off = 1; off < 64; off <<= 1) {
          const float nv = __shfl_down(val, off);
          if (lane + off < 64) val += nv;
        }
        Csuf[idx] = val + carry;              // sum_{j>=idx} W[j]
        carry += __shfl(val, 0);
      }
      if (lane == 0) Csuf[NC] = 0.f;
    }
    __syncthreads();

    float acc = 0.f;
    for (int kk = t; kk < NC; kk += 256) {
      const int mm = (i > kk) ? i : kk;
      acc += e[kk] * Csuf[mm + 1] * u[kk];
    }
    #pragma unroll
    for (int off = 32; off; off >>= 1) acc += __shfl_down(acc, off);
    __syncthreads();
    if (lane == 0) wred[wave] = acc;
    __syncthreads();
    if (t == 0)
      atomicAdd(out, wred[0] + wred[1] + wred[2] + wred[3]);
  }
}

// ===========================================================================
// Fallback path: the verified 5-dispatch pipeline, used only if the
// cooperative launch is rejected (e.g. capture-unsupported).
// ===========================================================================
__global__ __launch_bounds__(256) void big1(
    const float* __restrict__ x,
    const float* __restrict__ Wq, const float* __restrict__ Wk,
    const float* __restrict__ Wv, const float* __restrict__ Wc,
    float* __restrict__ partQK, float* __restrict__ hpart)
{
  const int b = blockIdx.x;
  const int t = threadIdx.x;

  if (b >= 640) {
    const int d0 = (b - 640) * 32;
    for (int ei = t; ei < DIM; ei += 256) {
      float s = 0.f;
      #pragma unroll
      for (int d = 0; d < 32; ++d)
        s = fmaf(Wv[(d0 + d) * DIM + ei], Wc[d0 + d], s);
      hpart[(b - 640) * DIM + ei] = s;
    }
    return;
  }

  __shared__ __align__(16) float As[32][68];
  __shared__ __align__(16) float Bs[32][68];

  const int z   = b / 40;
  const int rem = b % 40;
  const int i0  = (rem / 8) * 64;
  const int c0  = (rem % 8) * 64;
  const float* __restrict__ W = (z & 8) ? Wk : Wq;
  const int kb = (z & 7) * 64;

  const int sr = t >> 2;
  const int kc = (t & 3) << 3;
  const int ty = t >> 4;
  const int tx = t & 15;

  float acc[4][4] = {};
  const float* xp = x + (i0 + sr) * DIM + kc;
  const float* wp = W + (c0 + sr) * DIM + kc;

  for (int k0 = kb; k0 < kb + 64; k0 += 32) {
    const float4 xa = *(const float4*)(xp + k0);
    const float4 xb = *(const float4*)(xp + k0 + 4);
    const float4 wa = *(const float4*)(wp + k0);
    const float4 wb = *(const float4*)(wp + k0 + 4);
    __syncthreads();
    As[kc+0][sr]=xa.x; As[kc+1][sr]=xa.y; As[kc+2][sr]=xa.z; As[kc+3][sr]=xa.w;
    As[kc+4][sr]=xb.x; As[kc+5][sr]=xb.y; As[kc+6][sr]=xb.z; As[kc+7][sr]=xb.w;
    Bs[kc+0][sr]=wa.x; Bs[kc+1][sr]=wa.y; Bs[kc+2][sr]=wa.z; Bs[kc+3][sr]=wa.w;
    Bs[kc+4][sr]=wb.x; Bs[kc+5][sr]=wb.y; Bs[kc+6][sr]=wb.z; Bs[kc+7][sr]=wb.w;
    __syncthreads();
    #pragma unroll
    for (int kk = 0; kk < 32; ++kk) {
      const float4 a4 = *(const float4*)&As[kk][ty * 4];
      const float4 b4 = *(const float4*)&Bs[kk][tx * 4];
      const float a[4] = {a4.x, a4.y, a4.z, a4.w};
      const float bb[4] = {b4.x, b4.y, b4.z, b4.w};
      #pragma unroll
      for (int i = 0; i < 4; ++i)
        #pragma unroll
        for (int j = 0; j < 4; ++j)
          acc[i][j] = fmaf(a[i], bb[j], acc[i][j]);
    }
  }
  float* outq = partQK + (size_t)z * NC * DIM;
  #pragma unroll
  for (int i = 0; i < 4; ++i) {
    float4 o = {acc[i][0], acc[i][1], acc[i][2], acc[i][3]};
    *(float4*)&outq[(i0 + ty*4 + i) * DIM + c0 + tx*4] = o;
  }
}

__global__ __launch_bounds__(256) void reduce_qk(
    const float* __restrict__ part,
    const float* __restrict__ bq, const float* __restrict__ bk,
    float* __restrict__ q, float* __restrict__ k)
{
  const int mat = blockIdx.y;
  const int f   = blockIdx.x * 256 + threadIdx.x;
  const int row = f >> 7;
  const int col = (f & 127) * 4;
  const float* bias = mat ? bk : bq;
  float4 s = *(const float4*)&bias[col];
  const size_t off = (size_t)row * DIM + col;
  #pragma unroll
  for (int sp = 0; sp < 8; ++sp) {
    const float4 p = *(const float4*)&part[(size_t)(mat*8+sp) * NC * DIM + off];
    s.x += p.x; s.y += p.y; s.z += p.z; s.w += p.w;
  }
  float* out = mat ? k : q;
  *(float4*)&out[off] = s;
}

__global__ __launch_bounds__(256) void scores_u(
    const float* __restrict__ qbuf, const float* __restrict__ kbuf,
    const float* __restrict__ x,    const float* __restrict__ hpart,
    const float* __restrict__ bv,   const float* __restrict__ Wc,
    const float* __restrict__ bc,
    float* __restrict__ partS,
    float* __restrict__ u, float* __restrict__ out)
{
  const int b    = blockIdx.x;
  const int t    = threadIdx.x;
  const int lane = t & 63;
  const int wave = t >> 6;

  if (b >= 200) {
    __shared__ float red[12];
    const int r = b - 200;

    float cp = bv[t] * Wc[t] + bv[t + 256] * Wc[t + 256];
    float su = 0.f, sw = 0.f;
    for (int ei = t; ei < DIM; ei += 256) {
      float hs = 0.f;
      #pragma unroll
      for (int sp = 0; sp < 16; ++sp) hs += hpart[sp * DIM + ei];
      const float xv = x[r * DIM + ei];
      su = fmaf(xv, hs, su);
      sw = fmaf(xv, Wc[DIM + ei], sw);
    }
    #pragma unroll
    for (int off = 32; off; off >>= 1) {
      cp += __shfl_down(cp, off);
      su += __shfl_down(su, off);
      sw += __shfl_down(sw, off);
    }
    if (lane == 0) { red[wave] = cp; red[4 + wave] = su; red[8 + wave] = sw; }
    __syncthreads();
    if (t == 0) {
      const float c  = red[0] + red[1] + red[2] + red[3];
      const float sU = red[4] + red[5] + red[6] + red[7];
      float sW = red[8] + red[9] + red[10] + red[11];
      u[r] = sU + c;
      if (r == 0) sW += (float)NC * bc[0];
      atomicAdd(out, sW);
    }
    return;
  }

  __shared__ __align__(16) float As[32][68];
  __shared__ __align__(16) float Bs[32][68];

  const int z   = b / 25;
  const int rem = b % 25;
  const int i0  = (rem / 5) * 64;
  const int j0  = (rem % 5) * 64;
  const int kb  = z * 64;

  const int sr = t >> 2;
  const int kc = (t & 3) << 3;
  const int ty = t >> 4;
  const int tx = t & 15;

  float acc[4][4] = {};
  const float* qp = qbuf + (i0 + sr) * DIM + kc;
  const float* kp = kbuf + (j0 + sr) * DIM + kc;

  for (int k0 = kb; k0 < kb + 64; k0 += 32) {
    const float4 qa  = *(const float4*)(qp + k0);
    const float4 qb2 = *(const float4*)(qp + k0 + 4);
    const float4 ka  = *(const float4*)(kp + k0);
    const float4 kb4 = *(const float4*)(kp + k0 + 4);
    __syncthreads();
    As[kc+0][sr]=qa.x;  As[kc+1][sr]=qa.y;  As[kc+2][sr]=qa.z;  As[kc+3][sr]=qa.w;
    As[kc+4][sr]=qb2.x; As[kc+5][sr]=qb2.y; As[kc+6][sr]=qb2.z; As[kc+7][sr]=qb2.w;
    Bs[kc+0][sr]=ka.x;  Bs[kc+1][sr]=ka.y;  Bs[kc+2][sr]=ka.z;  Bs[kc+3][sr]=ka.w;
    Bs[kc+4][sr]=kb4.x; Bs[kc+5][sr]=kb4.y; Bs[kc+6][sr]=kb4.z; Bs[kc+7][sr]=kb4.w;
    __syncthreads();
    #pragma unroll
    for (int kk = 0; kk < 32; ++kk) {
      const float4 a4 = *(const float4*)&As[kk][ty * 4];
      const float4 b4 = *(const float4*)&Bs[kk][tx * 4];
      const float a[4] = {a4.x, a4.y, a4.z, a4.w};
      const float bb[4] = {b4.x, b4.y, b4.z, b4.w};
      #pragma unroll
      for (int i = 0; i < 4; ++i)
        #pragma unroll
        for (int j = 0; j < 4; ++j)
          acc[i][j] = fmaf(a[i], bb[j], acc[i][j]);
    }
  }
  float* outs = partS + (size_t)z * NC * NC;
  #pragma unroll
  for (int i = 0; i < 4; ++i) {
    float4 o = {acc[i][0], acc[i][1], acc[i][2], acc[i][3]};
    *(float4*)&outs[(i0 + ty*4 + i) * NC + j0 + tx*4] = o;
  }
}

__global__ __launch_bounds__(256) void row_ops3(
    const float* __restrict__ partS, const float* __restrict__ u,
    float* __restrict__ out)
{
  const int i    = blockIdx.x;
  const int t    = threadIdx.x;
  const int lane = t & 63;
  const int wave = t >> 6;

  __shared__ float e[NC];
  __shared__ float Warr[NC];
  __shared__ float Csuf[NC + 1];
  __shared__ float wred[4];

  const float scale = 0.044194173824159216f;
  for (int kk = t; kk < NC; kk += 256) {
    float s = 0.f;
    #pragma unroll
    for (int sp = 0; sp < 8; ++sp)
      s += partS[(size_t)sp * NC * NC + i * NC + kk];
    e[kk] = s * scale;
  }
  __syncthreads();

  float m = -1e30f;
  for (int kk = t; kk < NC; kk += 256) m = fmaxf(m, e[kk]);
  #pragma unroll
  for (int off = 32; off; off >>= 1) m = fmaxf(m, __shfl_down(m, off));
  if (lane == 0) wred[wave] = m;
  __syncthreads();
  m = fmaxf(fmaxf(wred[0], wred[1]), fmaxf(wred[2], wred[3]));

  for (int kk = t; kk < NC; kk += 256) e[kk] = __expf(e[kk] - m);
  __syncthreads();

  if (wave == 0) {
    float carry = 0.f;
    #pragma unroll
    for (int c = 0; c < 5; ++c) {
      const int idx = c * 64 + lane;
      float val = e[idx];
      #pragma unroll
      for (int off = 1; off < 64; off <<= 1) {
        const float nv = __shfl_up(val, off);
        if (lane >= off) val += nv;
      }
      const float incl = val + carry;
      const int j = idx + 1;
      if (j < NC) Warr[j] = (j > i) ? 1.f / ((float)j * incl) : 0.f;
      carry += __shfl(val, 63);
    }
    if (lane == 0) Warr[0] = 0.f;

    carry = 0.f;
    #pragma unroll
    for (int c = 4; c >= 0; --c) {
      const int idx = c * 64 + lane;
      float val = Warr[idx];
      #pragma unroll
      for (int off = 1; off < 64; off <<= 1) {
        const float nv = __shfl_down(val, off);
        if (lane + off < 64) val += nv;
      }
      Csuf[idx] = val + carry;
      carry += __shfl(val, 0);
    }
    if (lane == 0) Csuf[NC] = 0.f;
  }
  __syncthreads();

  float acc = 0.f;
  for (int kk = t; kk < NC; kk += 256) {
    const int mm = (i > kk) ? i : kk;
    acc += e[kk] * Csuf[mm + 1] * u[kk];
  }
  #pragma unroll
  for (int off = 32; off; off >>= 1) acc += __shfl_down(acc, off);
  __syncthreads();
  if (lane == 0) wred[wave] = acc;
  __syncthreads();
  if (t == 0)
    atomicAdd(out, wred[0] + wred[1] + wred[2] + wred[3]);
}

// ---------------------------------------------------------------------------
extern "C" void kernel_launch(void* const* d_in, const int* in_sizes, int n_in,
                              void* d_out, int out_size, void* d_ws, size_t ws_size,
                              hipStream_t stream) {
  const float* x  = (const float*)d_in[0];
  // d_in[1] = goal (unused by the reference forward)
  const float* Wq = (const float*)d_in[2];
  const float* bq = (const float*)d_in[3];
  const float* Wk = (const float*)d_in[4];
  const float* bk = (const float*)d_in[5];
  const float* Wv = (const float*)d_in[6];
  const float* bv = (const float*)d_in[7];
  const float* Wc = (const float*)d_in[8];
  const float* bc = (const float*)d_in[9];

  float* ws     = (float*)d_ws;
  float* partQK = ws;                          // 16*163840 = 2,621,440
  float* partS  = partQK + 16 * NC * DIM;      // 8*102400  =   819,200
  float* qbuf   = partS + 8 * NC * NC;         //   163,840
  float* kbuf   = qbuf + NC * DIM;             //   163,840
  float* hpart  = kbuf + NC * DIM;             //    8,192
  float* u      = hpart + 16 * DIM;            //      320
  float* out    = (float*)d_out;

  void* args[] = {
    (void*)&x,
    (void*)&Wq, (void*)&bq, (void*)&Wk, (void*)&bk,
    (void*)&Wv, (void*)&bv, (void*)&Wc, (void*)&bc,
    (void*)&partQK, (void*)&partS, (void*)&qbuf, (void*)&kbuf,
    (void*)&hpart, (void*)&u, (void*)&out
  };

  hipError_t err = hipLaunchCooperativeKernel(
      (const void*)fused_all, dim3(656), dim3(256), args, 0, stream);

  if (err != hipSuccess) {
    // Verified 5-dispatch fallback.
    hipMemsetAsync(out, 0, sizeof(float), stream);
    big1<<<656, 256, 0, stream>>>(x, Wq, Wk, Wv, Wc, partQK, hpart);
    reduce_qk<<<dim3(160, 2), 256, 0, stream>>>(partQK, bq, bk, qbuf, kbuf);
    scores_u<<<520, 256, 0, stream>>>(qbuf, kbuf, x, hpart, bv, Wc, bc,
                                      partS, u, out);
    row_ops3<<<NC, 256, 0, stream>>>(partS, u, out);
  }
}

// Round 2
// 119.592 us; speedup vs baseline: 2.9472x; 2.9472x over previous
//
#include <hip/hip_runtime.h>

#define NC 320   // coalition size
#define DIM 512

// ===========================================================================
// K1 "big1": verified R4 body, unchanged, plus out-zero (replaces memset).
// grid 656 x 256.
//   b < 640 : split-K partials for q=x@Wq^T, k=x@Wk^T. z=b/40 (mat=z>>3,
//             ksplit=z&7), rem=b%40: i0=(rem/8)*64, c0=(rem%8)*64.
//             64x64 tile, BK=32, 4x4 micro, float4 stores to private slice.
//   b >= 640: hpart[b-640][e] = sum over a 32-wide d-chunk of Wv[d,e]*wA[d].
// ===========================================================================
__global__ __launch_bounds__(256) void big1(
    const float* __restrict__ x,
    const float* __restrict__ Wq, const float* __restrict__ Wk,
    const float* __restrict__ Wv, const float* __restrict__ Wc,
    float* __restrict__ partQK,   // [16][NC][DIM]
    float* __restrict__ hpart,    // [16][DIM]
    float* __restrict__ out)
{
  const int b = blockIdx.x;
  const int t = threadIdx.x;

  if (b == 0 && t == 0) out[0] = 0.f;   // replaces hipMemsetAsync; visible to
                                        // K2/K3 atomics via dispatch ordering.

  if (b >= 640) {   // ---- hpart ----
    const int d0 = (b - 640) * 32;
    for (int ei = t; ei < DIM; ei += 256) {
      float s = 0.f;
      #pragma unroll
      for (int d = 0; d < 32; ++d)
        s = fmaf(Wv[(d0 + d) * DIM + ei], Wc[d0 + d], s);
      hpart[(b - 640) * DIM + ei] = s;
    }
    return;
  }

  // ---- split-K gemm partials (verified) ----
  __shared__ __align__(16) float As[32][68];   // [kk][row]
  __shared__ __align__(16) float Bs[32][68];   // [kk][col]

  const int z   = b / 40;
  const int rem = b % 40;
  const int i0  = (rem / 8) * 64;
  const int c0  = (rem % 8) * 64;
  const float* __restrict__ W = (z & 8) ? Wk : Wq;
  const int kb = (z & 7) * 64;

  const int sr = t >> 2;            // staged row/col 0..63
  const int kc = (t & 3) << 3;      // staged k offset 0,8,16,24
  const int ty = t >> 4;            // 0..15 row quad
  const int tx = t & 15;            // 0..15 col quad

  float acc[4][4] = {};
  const float* xp = x + (i0 + sr) * DIM + kc;
  const float* wp = W + (c0 + sr) * DIM + kc;

  for (int k0 = kb; k0 < kb + 64; k0 += 32) {
    const float4 xa = *(const float4*)(xp + k0);
    const float4 xb = *(const float4*)(xp + k0 + 4);
    const float4 wa = *(const float4*)(wp + k0);
    const float4 wb = *(const float4*)(wp + k0 + 4);
    __syncthreads();
    As[kc+0][sr]=xa.x; As[kc+1][sr]=xa.y; As[kc+2][sr]=xa.z; As[kc+3][sr]=xa.w;
    As[kc+4][sr]=xb.x; As[kc+5][sr]=xb.y; As[kc+6][sr]=xb.z; As[kc+7][sr]=xb.w;
    Bs[kc+0][sr]=wa.x; Bs[kc+1][sr]=wa.y; Bs[kc+2][sr]=wa.z; Bs[kc+3][sr]=wa.w;
    Bs[kc+4][sr]=wb.x; Bs[kc+5][sr]=wb.y; Bs[kc+6][sr]=wb.z; Bs[kc+7][sr]=wb.w;
    __syncthreads();
    #pragma unroll
    for (int kk = 0; kk < 32; ++kk) {
      const float4 a4 = *(const float4*)&As[kk][ty * 4];
      const float4 b4 = *(const float4*)&Bs[kk][tx * 4];
      const float a[4] = {a4.x, a4.y, a4.z, a4.w};
      const float bb[4] = {b4.x, b4.y, b4.z, b4.w};
      #pragma unroll
      for (int i = 0; i < 4; ++i)
        #pragma unroll
        for (int j = 0; j < 4; ++j)
          acc[i][j] = fmaf(a[i], bb[j], acc[i][j]);
    }
  }
  float* outq = partQK + (size_t)z * NC * DIM;
  #pragma unroll
  for (int i = 0; i < 4; ++i) {
    float4 o = {acc[i][0], acc[i][1], acc[i][2], acc[i][3]};
    *(float4*)&outq[(i0 + ty*4 + i) * DIM + c0 + tx*4] = o;
  }
}

// ===========================================================================
// K2 "reduce_qk_u": grid 640 x 256.
//   b < 320 : verified reduce_qk body. mat=b/160, f=(b%160)*256+t.
//             q/k = sum of 8 partials + bias (bias first, sp 0..7 — same
//             order as before, bitwise identical output).
//   b >= 320: verified u/uw body (was scores_u b>=200), r=b-320.
//             u[r] = x[r].h + c; atomicAdd(out, x[r].wx) (+NC*bc at r==0).
// ===========================================================================
__global__ __launch_bounds__(256) void reduce_qk_u(
    const float* __restrict__ partQK,
    const float* __restrict__ bq, const float* __restrict__ bk,
    const float* __restrict__ x,  const float* __restrict__ hpart,
    const float* __restrict__ bv, const float* __restrict__ Wc,
    const float* __restrict__ bc,
    float* __restrict__ q, float* __restrict__ k,
    float* __restrict__ u, float* __restrict__ out)
{
  const int b = blockIdx.x;
  const int t = threadIdx.x;

  if (b < 320) {   // ---- q/k reduce (verified) ----
    const int mat = b / 160;
    const int f   = (b % 160) * 256 + t;   // float4 index
    const int row = f >> 7;                // 128 float4 per row
    const int col = (f & 127) * 4;
    const float* bias = mat ? bk : bq;
    float4 s = *(const float4*)&bias[col];
    const size_t off = (size_t)row * DIM + col;
    #pragma unroll
    for (int sp = 0; sp < 8; ++sp) {
      const float4 p = *(const float4*)&partQK[(size_t)(mat*8+sp) * NC * DIM + off];
      s.x += p.x; s.y += p.y; s.z += p.z; s.w += p.w;
    }
    float* o = mat ? k : q;
    *(float4*)&o[off] = s;
    return;
  }

  // ---- u / uw (verified body) ----
  __shared__ float red[12];
  const int lane = t & 63;
  const int wave = t >> 6;
  const int r = b - 320;

  float cp = bv[t] * Wc[t] + bv[t + 256] * Wc[t + 256];
  float su = 0.f, sw = 0.f;
  for (int ei = t; ei < DIM; ei += 256) {
    float hs = 0.f;
    #pragma unroll
    for (int sp = 0; sp < 16; ++sp) hs += hpart[sp * DIM + ei];
    const float xv = x[r * DIM + ei];
    su = fmaf(xv, hs, su);
    sw = fmaf(xv, Wc[DIM + ei], sw);
  }
  #pragma unroll
  for (int off = 32; off; off >>= 1) {
    cp += __shfl_down(cp, off);
    su += __shfl_down(su, off);
    sw += __shfl_down(sw, off);
  }
  if (lane == 0) { red[wave] = cp; red[4 + wave] = su; red[8 + wave] = sw; }
  __syncthreads();
  if (t == 0) {
    const float c  = red[0] + red[1] + red[2] + red[3];
    const float sU = red[4] + red[5] + red[6] + red[7];
    float sW = red[8] + red[9] + red[10] + red[11];
    u[r] = sU + c;
    if (r == 0) sW += (float)NC * bc[0];
    atomicAdd(out, sW);
  }
}

// ===========================================================================
// K3 "rows_fused": grid 160 x 320. Replaces the scores split-K GEMM dispatch
// AND row_ops3 — no partS round-trip.
//
// Block bi owns query rows iA=bi, iB=bi+160. Stages q[iA],q[iB] in LDS, then
// thread t computes S[iA][t], S[iB][t] directly by streaming k row t out of
// L2 (k = 640 KB, L2-resident; 160 blocks share it).
//
// Bitwise-identical arithmetic to the old path:
//   - 8 chunk accumulators sa[z]/sb[z], fmaf chain over d ascending within
//     each 64-chunk == old 4x4 micro-kernel's per-(i,j) accumulation order
//     for split z (kb=z*64, k0 then k0+32, kk ascending).
//   - e = (((sa[0]+sa[1])+sa[2])+...)*scale == row_ops3's s=0; s+=partS[sp]
//     ascending (0+p0 == p0 exactly).
//   - max / exp / scans / contraction: verbatim row_ops3 code restricted to
//     t<256 so every reduction tree has identical addend order.
// ===========================================================================
__global__ __launch_bounds__(320) void rows_fused(
    const float* __restrict__ qbuf, const float* __restrict__ kbuf,
    const float* __restrict__ u, float* __restrict__ out)
{
  const int bi   = blockIdx.x;     // 0..159
  const int t    = threadIdx.x;    // 0..319
  const int lane = t & 63;
  const int wave = t >> 6;

  const int iA = bi;
  const int iB = bi + 160;

  __shared__ __align__(16) float qA[DIM];
  __shared__ __align__(16) float qB[DIM];
  __shared__ float eA[NC];
  __shared__ float eB[NC];
  __shared__ float Warr[NC];
  __shared__ float Csuf[NC + 1];
  __shared__ float wred[4];

  // ---- stage q rows ----
  for (int ei = t; ei < DIM; ei += 320) {
    qA[ei] = qbuf[iA * DIM + ei];
    qB[ei] = qbuf[iB * DIM + ei];
  }
  __syncthreads();

  // ---- score row entries: thread t owns column j = t for both rows ----
  {
    const float* kj = kbuf + (size_t)t * DIM;
    float sa[8], sb[8];
    #pragma unroll
    for (int z = 0; z < 8; ++z) {
      float a = 0.f, bacc = 0.f;
      #pragma unroll
      for (int dd = 0; dd < 64; dd += 4) {
        const int d = z * 64 + dd;
        const float4 kv  = *(const float4*)(kj + d);
        const float4 qa4 = *(const float4*)&qA[d];
        const float4 qb4 = *(const float4*)&qB[d];
        a    = fmaf(qa4.x, kv.x, a);
        a    = fmaf(qa4.y, kv.y, a);
        a    = fmaf(qa4.z, kv.z, a);
        a    = fmaf(qa4.w, kv.w, a);
        bacc = fmaf(qb4.x, kv.x, bacc);
        bacc = fmaf(qb4.y, kv.y, bacc);
        bacc = fmaf(qb4.z, kv.z, bacc);
        bacc = fmaf(qb4.w, kv.w, bacc);
      }
      sa[z] = a; sb[z] = bacc;
    }
    const float scale = 0.044194173824159216f;  // 1/sqrt(512)
    float sA = sa[0], sB = sb[0];
    #pragma unroll
    for (int z = 1; z < 8; ++z) { sA += sa[z]; sB += sb[z]; }
    eA[t] = sA * scale;
    eB[t] = sB * scale;
  }
  __syncthreads();

  // ---- per-row tail: verbatim row_ops3, twice ----
  for (int rsel = 0; rsel < 2; ++rsel) {
    float* e    = rsel ? eB : eA;
    const int i = rsel ? iB : iA;

    float m = -1e30f;
    if (t < 256) {
      for (int kk = t; kk < NC; kk += 256) m = fmaxf(m, e[kk]);
      #pragma unroll
      for (int off = 32; off; off >>= 1) m = fmaxf(m, __shfl_down(m, off));
      if (lane == 0) wred[wave] = m;
    }
    __syncthreads();
    m = fmaxf(fmaxf(wred[0], wred[1]), fmaxf(wred[2], wred[3]));

    if (t < 256)
      for (int kk = t; kk < NC; kk += 256) e[kk] = __expf(e[kk] - m);
    __syncthreads();

    if (wave == 0) {
      float carry = 0.f;
      #pragma unroll
      for (int c = 0; c < 5; ++c) {
        const int idx = c * 64 + lane;
        float val = e[idx];
        #pragma unroll
        for (int off = 1; off < 64; off <<= 1) {
          const float nv = __shfl_up(val, off);
          if (lane >= off) val += nv;
        }
        const float incl = val + carry;       // prefix sum S[idx+1]
        const int j = idx + 1;
        if (j < NC) Warr[j] = (j > i) ? 1.f / ((float)j * incl) : 0.f;
        carry += __shfl(val, 63);
      }
      if (lane == 0) Warr[0] = 0.f;

      carry = 0.f;
      #pragma unroll
      for (int c = 4; c >= 0; --c) {
        const int idx = c * 64 + lane;
        float val = Warr[idx];
        #pragma unroll
        for (int off = 1; off < 64; off <<= 1) {
          const float nv = __shfl_down(val, off);
          if (lane + off < 64) val += nv;
        }
        Csuf[idx] = val + carry;              // sum_{j>=idx} W[j]
        carry += __shfl(val, 0);
      }
      if (lane == 0) Csuf[NC] = 0.f;
    }
    __syncthreads();

    float acc = 0.f;
    if (t < 256) {
      for (int kk = t; kk < NC; kk += 256) {
        const int mm = (i > kk) ? i : kk;
        acc += e[kk] * Csuf[mm + 1] * u[kk];
      }
      #pragma unroll
      for (int off = 32; off; off >>= 1) acc += __shfl_down(acc, off);
    }
    __syncthreads();
    if (t < 256 && lane == 0) wred[wave] = acc;
    __syncthreads();
    if (t == 0)
      atomicAdd(out, wred[0] + wred[1] + wred[2] + wred[3]);
    __syncthreads();   // protect Warr/Csuf/wred before next row
  }
}

// ---------------------------------------------------------------------------
extern "C" void kernel_launch(void* const* d_in, const int* in_sizes, int n_in,
                              void* d_out, int out_size, void* d_ws, size_t ws_size,
                              hipStream_t stream) {
  const float* x  = (const float*)d_in[0];
  // d_in[1] = goal (unused by the reference forward)
  const float* Wq = (const float*)d_in[2];
  const float* bq = (const float*)d_in[3];
  const float* Wk = (const float*)d_in[4];
  const float* bk = (const float*)d_in[5];
  const float* Wv = (const float*)d_in[6];
  const float* bv = (const float*)d_in[7];
  const float* Wc = (const float*)d_in[8];
  const float* bc = (const float*)d_in[9];

  float* ws     = (float*)d_ws;
  float* partQK = ws;                          // 16*163840 = 2,621,440 floats
  float* qbuf   = partQK + 16 * NC * DIM;      //   163,840
  float* kbuf   = qbuf + NC * DIM;             //   163,840
  float* hpart  = kbuf + NC * DIM;             //     8,192
  float* u      = hpart + 16 * DIM;            //       320
  float* out    = (float*)d_out;

  big1<<<656, 256, 0, stream>>>(x, Wq, Wk, Wv, Wc, partQK, hpart, out);
  reduce_qk_u<<<640, 256, 0, stream>>>(partQK, bq, bk, x, hpart, bv, Wc, bc,
                                       qbuf, kbuf, u, out);
  rows_fused<<<160, 320, 0, stream>>>(qbuf, kbuf, u, out);
}